// Round 4
// baseline (281.516 us; speedup 1.0000x reference)
//
#include <hip/hip_runtime.h>

#define T 4
#define D 1024
#define NN 256
#define K 64
#define V 32000
// derived
#define VK (V*K)          // 2048000
#define TD (T*D)          // 4096

__device__ __forceinline__ float jexp(float x) {
    // jax_exp: clip(exp(clip(x,-700,700)), 1e-6)
    x = fminf(fmaxf(x, -700.0f), 700.0f);
    return fmaxf(expf(x), 1e-6f);
}

// ws layout (floats): S[256] | S_part[500*64] | delta u32[T*V*32]  (16,384,000 B)
// delta row (per t,w): 128 B = [plus u8x4 ×16][minus u8x4 ×16] — one token's
// +1/-1 atomic pair lands in two ADJACENT 64B lines (same page/sector).

// ---------------- colsum partials + delta-buffer zeroing ----------------
// grid = T*125 = 500 blocks; each block covers 256 consecutive v-rows of one t.
__global__ void phi_colsum_kernel(const float* __restrict__ phi,
                                  float* __restrict__ S_part,
                                  unsigned int* __restrict__ delta)
{
    int blk = blockIdx.x;
    int tid = threadIdx.x;

    // ---- zero the 16 MB delta region: 8 uint4 per thread ----
    {
        uint4* dz = (uint4*)delta;
        int g = blk * 256 + tid;
        uint4 z4 = make_uint4(0u, 0u, 0u, 0u);
        #pragma unroll
        for (int i = 0; i < 8; ++i)
            dz[g + i * 128000] = z4;
    }

    // ---- column sums of exp(phi) ----
    int t = blk / 125;
    int vbase = (blk % 125) * 256;
    int k = tid & 63;
    int r = tid >> 6;               // 0..3
    const float* base = phi + (size_t)t * VK;
    float s = 0.0f;
    #pragma unroll 4
    for (int it = 0; it < 64; ++it) {
        int v = vbase + it * 4 + r;
        s += expf(base[v * K + k]);         // coalesced: tid-consecutive addrs
    }
    __shared__ float sm[256];
    sm[tid] = s;
    __syncthreads();
    if (tid < 64) {
        S_part[blk * 64 + tid] = sm[tid] + sm[tid + 64] +
                                 sm[tid + 128] + sm[tid + 192];
    }
}

// ---------------- fused eta SGLD + MH resampling ----------------
// one block per (t,d) document, 256 threads = N tokens.
// All token loads (incl. both scattered phi gathers) issue BEFORE the eta
// barrier: pre/prop1 come straight from global Z (row is L1-hot from the
// coalesced load), so the gather latency hides under the eta softmax phase.
__global__ void mh_eta_kernel(const int* __restrict__ W, const int* __restrict__ Z,
                              const int* __restrict__ pwi, const int* __restrict__ ptop,
                              const float* __restrict__ u, const float* __restrict__ phi,
                              const float* __restrict__ eta,
                              const float* __restrict__ alpha,
                              const float* __restrict__ noise_eta,
                              const float* __restrict__ CDK,
                              float* __restrict__ eta_new,
                              float* __restrict__ CDK_new,
                              unsigned int* __restrict__ delta,
                              float* __restrict__ z_out)
{
    int r = blockIdx.x;             // t*D + d
    int t = r >> 10;                // D = 1024
    int n = threadIdx.x;

    __shared__ float esh[K];
    __shared__ int   hist[K];

    // ---- early independent token loads (no barrier dependency) ----
    int w     = W[r * NN + n];
    int pre   = Z[r * NN + n];          // coalesced; makes the row L1-hot
    int pw    = pwi[r * NN + n];
    int prop1 = Z[r * NN + pw];         // random-in-row: L1 hit
    int pt    = ptop[r * NN + n];
    float2 uu = ((const float2*)u)[(size_t)r * NN + n];

    const float* prow = phi + ((size_t)t * V + w) * K;
    float f1 = prow[prop1];             // scattered gathers: in flight during eta
    float f0 = prow[pre];

    float cdk = 0.0f;
    if (n < 64) {
        // ---- eta SGLD update for this row, wave 0 only ----
        float x = eta[r * K + n];
        float m = x;
        #pragma unroll
        for (int off = 32; off >= 1; off >>= 1)
            m = fmaxf(m, __shfl_xor(m, off, 64));
        float e = expf(x - m);
        float s = e;
        #pragma unroll
        for (int off = 32; off >= 1; off >>= 1)
            s += __shfl_xor(s, off, 64);
        float smx = e / s;
        cdk = CDK[r * K + n];
        float grad  = cdk - (float)NN * smx;
        float prior = alpha[t * K + n] - x;          // ETA_VAR = 1
        float en = x + 0.005f * (grad + prior) + noise_eta[r] * 0.01f;
        esh[n] = en;
        eta_new[r * K + n] = en;
    } else if (n < 128) {
        hist[n - 64] = 0;
    }
    __syncthreads();

    float a1 = jexp(f1) / jexp(f0);
    int k1 = (uu.x < a1) ? prop1 : pre;

    float a2 = jexp(esh[pt]) / jexp(esh[k1]);
    int z = (uu.y < a2) ? pt : k1;

    // only LDS atomics before the final barrier
    atomicAdd(&hist[z], 1);
    atomicAdd(&hist[pre], -1);
    __syncthreads();

    // ---- phase C: global writes, fire-and-forget ----
    z_out[r * NN + n] = (float)z;
    if (z != pre) {   // net-zero when equal
        size_t rowbase = ((size_t)t * V + w) * 32;   // 32 u32 = 128 B per row
        atomicAdd(&delta[rowbase + (z   >> 2)],      1u << ((z   & 3) * 8));
        atomicAdd(&delta[rowbase + 16 + (pre >> 2)], 1u << ((pre & 3) * 8));
    }
    if (n < K) {
        CDK_new[r * K + n] = cdk + (float)hist[n];   // block owns this row
    }
}

// ---------------- S finalize + CK_new = CK + sum_d (CDKn - CDK) ----------------
// grid = 4 blocks (one per t), 1024 threads.
__global__ void reduce_kernel(const float* __restrict__ S_part,
                              const float* __restrict__ CDKn,
                              const float* __restrict__ CDK,
                              const float* __restrict__ CK,
                              float* __restrict__ S,
                              float* __restrict__ CK_new)
{
    int t = blockIdx.x;
    int tid = threadIdx.x;

    if (tid < 64) {
        float s = 0.0f;
        #pragma unroll 5
        for (int i = 0; i < 125; ++i)
            s += S_part[(t * 125 + i) * 64 + tid];
        S[t * 64 + tid] = s;
    }

    int k  = tid & 63;
    int dl = tid >> 6;              // 0..15
    float s = 0.0f;
    #pragma unroll 4
    for (int i = 0; i < 64; ++i) {
        int d = dl + i * 16;
        size_t idx = ((size_t)t * D + d) * 64 + k;
        s += CDKn[idx] - CDK[idx];
    }
    __shared__ float sm[1024];
    sm[tid] = s;
    __syncthreads();
    if (tid < 64) {
        float tot = 0.0f;
        #pragma unroll
        for (int j = 0; j < 16; ++j) tot += sm[j * 64 + tid];
        CK_new[t * 64 + tid] = CK[t * 64 + tid] + tot;
    }
}

// ---------------- phi SGLD update + CWK_new materialization ----------------
// grid = VK/1024 = 2000 blocks; each thread owns 4 consecutive (v,k) slots.
__global__ void phi_update_kernel(const float* __restrict__ phi,
                                  const float* __restrict__ CWK,
                                  const unsigned int* __restrict__ delta,
                                  const float* __restrict__ CKn,
                                  const float* __restrict__ S,
                                  const float* __restrict__ noise_phi,
                                  float* __restrict__ phi_new,
                                  float* __restrict__ CWK_new)
{
    int i4 = blockIdx.x * 256 + threadIdx.x;    // float4 index, < VK/4 = 512000
    int kg = i4 & 15;                           // k-group: k = 4*kg .. 4*kg+3
    int v  = i4 >> 4;                           // word row, < V
    const float eps = 0.01f;
    const float half_eps = 0.005f;
    const float sig = 1.0f / 1.01f;             // phi_sigma / PHI_VAR

    const float4* phi4  = (const float4*)phi;
    const float4* cwk4  = (const float4*)CWK;
    const float4* ck4   = (const float4*)CKn;
    const float4* s4    = (const float4*)S;
    float4*       out4  = (float4*)phi_new;
    float4*       cwkn4 = (float4*)CWK_new;

    float4 p0 = phi4[i4];
    float4 p1 = phi4[i4 +     512000];
    float4 p2 = phi4[i4 + 2 * 512000];
    float4 p3 = phi4[i4 + 3 * 512000];

    float4 c0 = cwk4[i4];
    float4 c1 = cwk4[i4 +     512000];
    float4 c2 = cwk4[i4 + 2 * 512000];
    float4 c3 = cwk4[i4 + 3 * 512000];

    // interleaved delta rows: ((t*V + v)*32) + kg  (plus)  / +16 (minus)
    size_t r0b = (size_t)v * 32;
    unsigned int pl0 = delta[r0b + kg],                 mi0 = delta[r0b + 16 + kg];
    unsigned int pl1 = delta[r0b + (size_t)V*32 + kg],  mi1 = delta[r0b + (size_t)V*32 + 16 + kg];
    unsigned int pl2 = delta[r0b + (size_t)2*V*32 + kg],mi2 = delta[r0b + (size_t)2*V*32 + 16 + kg];
    unsigned int pl3 = delta[r0b + (size_t)3*V*32 + kg],mi3 = delta[r0b + (size_t)3*V*32 + 16 + kg];

    float4 ckn0 = ck4[kg],      ckn1 = ck4[16 + kg];
    float4 ckn2 = ck4[32 + kg], ckn3 = ck4[48 + kg];
    float4 ss0 = s4[kg],        ss1 = s4[16 + kg];
    float4 ss2 = s4[32 + kg],   ss3 = s4[48 + kg];

    float np0 = noise_phi[0] * eps, np1 = noise_phi[1] * eps;
    float np2 = noise_phi[2] * eps, np3 = noise_phi[3] * eps;

    float4 o0, o1, o2, o3, w0, w1, w2, w3;
    #pragma unroll
    for (int j = 0; j < 4; ++j) {
        int sh = j * 8;
        float q0 = (&p0.x)[j], q1 = (&p1.x)[j], q2 = (&p2.x)[j], q3 = (&p3.x)[j];
        float d0 = (float)((pl0 >> sh) & 255u) - (float)((mi0 >> sh) & 255u);
        float d1 = (float)((pl1 >> sh) & 255u) - (float)((mi1 >> sh) & 255u);
        float d2 = (float)((pl2 >> sh) & 255u) - (float)((mi2 >> sh) & 255u);
        float d3 = (float)((pl3 >> sh) & 255u) - (float)((mi3 >> sh) & 255u);
        float cw0 = (&c0.x)[j] + d0;
        float cw1 = (&c1.x)[j] + d1;
        float cw2 = (&c2.x)[j] + d2;
        float cw3 = (&c3.x)[j] + d3;
        (&w0.x)[j] = cw0; (&w1.x)[j] = cw1; (&w2.x)[j] = cw2; (&w3.x)[j] = cw3;

        float g0 = cw0 - (&ckn0.x)[j] * (expf(q0) / (&ss0.x)[j]);
        float g1 = cw1 - (&ckn1.x)[j] * (expf(q1) / (&ss1.x)[j]);
        float g2 = cw2 - (&ckn2.x)[j] * (expf(q2) / (&ss2.x)[j]);
        float g3 = cw3 - (&ckn3.x)[j] * (expf(q3) / (&ss3.x)[j]);

        float r0 = q0 + half_eps * (g0 + 2.0f * q1 * sig - 2.0f * q0) + np0;
        float r1 = q1 + half_eps * (g1 + q2 + r0 - 2.0f * q1)         + np1;
        float r2 = q2 + half_eps * (g2 + q3 + r1 - 2.0f * q2)         + np2;
        float r3 = q3 + half_eps * (g3 + r2 - q3)                      + np3;

        (&o0.x)[j] = r0; (&o1.x)[j] = r1; (&o2.x)[j] = r2; (&o3.x)[j] = r3;
    }

    out4[i4]              = o0;
    out4[i4 +     512000] = o1;
    out4[i4 + 2 * 512000] = o2;
    out4[i4 + 3 * 512000] = o3;

    cwkn4[i4]              = w0;
    cwkn4[i4 +     512000] = w1;
    cwkn4[i4 + 2 * 512000] = w2;
    cwkn4[i4 + 3 * 512000] = w3;
}

extern "C" void kernel_launch(void* const* d_in, const int* in_sizes, int n_in,
                              void* d_out, int out_size, void* d_ws, size_t ws_size,
                              hipStream_t stream)
{
    const int*   W         = (const int*)  d_in[0];
    const int*   Z         = (const int*)  d_in[1];
    const int*   pwi       = (const int*)  d_in[2];
    const int*   ptop      = (const int*)  d_in[3];
    const float* u_mh      = (const float*)d_in[4];
    const float* noise_eta = (const float*)d_in[5];
    const float* noise_phi = (const float*)d_in[6];
    const float* alpha     = (const float*)d_in[7];
    const float* phi       = (const float*)d_in[8];
    const float* eta       = (const float*)d_in[9];
    const float* CDK       = (const float*)d_in[10];
    const float* CWK       = (const float*)d_in[11];
    const float* CK        = (const float*)d_in[12];

    float* out     = (float*)d_out;
    float* eta_new = out;                               // T*D*K   = 262144
    float* phi_new = out + 262144;                      // T*V*K   = 8192000
    float* CDK_new = out + 8454144;                     // T*D*K   = 262144
    float* CWK_new = out + 8716288;                     // T*V*K   = 8192000
    float* CK_new  = out + 16908288;                    // T*K     = 256
    float* z_out   = out + 16908544;                    // T*D*N   = 1048576

    float* ws      = (float*)d_ws;
    float* S       = ws;                                // 256 floats
    float* S_part  = ws + 256;                          // 500*64 floats
    unsigned int* delta = (unsigned int*)(ws + 256 + 32000);   // 16,384,000 B

    phi_colsum_kernel<<<T * 125, 256, 0, stream>>>(phi, S_part, delta);
    mh_eta_kernel<<<TD, 256, 0, stream>>>(W, Z, pwi, ptop, u_mh, phi,
                                          eta, alpha, noise_eta, CDK,
                                          eta_new, CDK_new, delta, z_out);
    reduce_kernel<<<4, 1024, 0, stream>>>(S_part, CDK_new, CDK, CK, S, CK_new);
    phi_update_kernel<<<VK / 1024, 256, 0, stream>>>(phi, CWK, delta,
                                                     CK_new, S, noise_phi,
                                                     phi_new, CWK_new);
}

// Round 5
// 270.651 us; speedup vs baseline: 1.0401x; 1.0401x over previous
//
#include <hip/hip_runtime.h>

#define T 4
#define D 1024
#define NN 256
#define K 64
#define V 32000
// derived
#define VK (V*K)          // 2048000
#define TD (T*D)          // 4096

__device__ __forceinline__ float jexp(float x) {
    // jax_exp: clip(exp(clip(x,-700,700)), 1e-6)
    x = fminf(fmaxf(x, -700.0f), 700.0f);
    return fmaxf(expf(x), 1e-6f);
}

// ws layout (floats): S[256] | S_part[500*64] | plus u8[T*V*K] | minus u8[T*V*K]
// plus/minus are SEPARATE 8MB regions (R3 layout): a token's +1/-1 pair lands in
// different memory channels and proceeds in parallel. (R4's adjacent-line pairing
// serialized the pair in one channel: -7 us. Keep them spread.)

// ---------------- colsum partials + delta zeroing + CK_new init ----------------
// grid = T*125 = 500 blocks; each block covers 256 consecutive v-rows of one t.
__global__ void phi_colsum_kernel(const float* __restrict__ phi,
                                  float* __restrict__ S_part,
                                  unsigned int* __restrict__ delta,  // plus||minus
                                  const float* __restrict__ CK,
                                  float* __restrict__ CK_new)
{
    int blk = blockIdx.x;
    int tid = threadIdx.x;

    // ---- zero the 16 MB plus/minus region: 8 uint4 per thread ----
    {
        uint4* dz = (uint4*)delta;
        int g = blk * 256 + tid;
        uint4 z4 = make_uint4(0u, 0u, 0u, 0u);
        #pragma unroll
        for (int i = 0; i < 8; ++i)
            dz[g + i * 128000] = z4;
    }
    if (blk == 0) CK_new[tid] = CK[tid];    // T*K = 256 = blockDim

    // ---- column sums of exp(phi) ----
    int t = blk / 125;
    int vbase = (blk % 125) * 256;
    int k = tid & 63;
    int r = tid >> 6;               // 0..3
    const float* base = phi + (size_t)t * VK;
    float s = 0.0f;
    #pragma unroll 4
    for (int it = 0; it < 64; ++it) {
        int v = vbase + it * 4 + r;
        s += expf(base[v * K + k]);         // coalesced: tid-consecutive addrs
    }
    __shared__ float sm[256];
    sm[tid] = s;
    __syncthreads();
    if (tid < 64) {
        S_part[blk * 64 + tid] = sm[tid] + sm[tid + 64] +
                                 sm[tid + 128] + sm[tid + 192];
    }
}

// ---------------- fused eta SGLD + MH resampling ----------------
// one block per (t,d) document, 256 threads = N tokens.
// XCD-locality swizzle: hardware blocks round-robin over 8 XCDs; remap so each
// XCD processes documents of a SINGLE t -> phi gathers hit a ~5MB working set
// in the XCD's 4MB L2 instead of the full 32MB (beyond-L2 traffic).
__global__ void mh_eta_kernel(const int* __restrict__ W, const int* __restrict__ Z,
                              const int* __restrict__ pwi, const int* __restrict__ ptop,
                              const float* __restrict__ u, const float* __restrict__ phi,
                              const float* __restrict__ eta,
                              const float* __restrict__ alpha,
                              const float* __restrict__ noise_eta,
                              const float* __restrict__ CDK,
                              float* __restrict__ eta_new,
                              float* __restrict__ CDK_new,
                              unsigned int* __restrict__ plus,
                              unsigned int* __restrict__ minus,
                              float* __restrict__ z_out)
{
    int b = blockIdx.x;
    int r = ((b & 7) << 9) | (b >> 3);   // XCD gets one contiguous t-half
    int t = r >> 10;                     // D = 1024
    int n = threadIdx.x;

    __shared__ float esh[K];
    __shared__ int   hist[K];

    // ---- early independent token loads (issue before the eta barrier) ----
    int w     = W[r * NN + n];
    int pre   = Z[r * NN + n];          // coalesced; makes the row L1-hot
    int pw    = pwi[r * NN + n];
    int prop1 = Z[r * NN + pw];         // random-in-row: L1 hit
    int pt    = ptop[r * NN + n];
    float2 uu = ((const float2*)u)[(size_t)r * NN + n];

    const float* prow = phi + ((size_t)t * V + w) * K;
    float f1 = prow[prop1];             // scattered gathers, in flight during eta
    float f0 = prow[pre];

    float cdk = 0.0f;
    if (n < 64) {
        // ---- eta SGLD update for this row, wave 0 only ----
        float x = eta[r * K + n];
        float m = x;
        #pragma unroll
        for (int off = 32; off >= 1; off >>= 1)
            m = fmaxf(m, __shfl_xor(m, off, 64));
        float e = expf(x - m);
        float s = e;
        #pragma unroll
        for (int off = 32; off >= 1; off >>= 1)
            s += __shfl_xor(s, off, 64);
        float smx = e / s;
        cdk = CDK[r * K + n];
        float grad  = cdk - (float)NN * smx;
        float prior = alpha[t * K + n] - x;          // ETA_VAR = 1
        float en = x + 0.005f * (grad + prior) + noise_eta[r] * 0.01f;
        esh[n] = en;
        eta_new[r * K + n] = en;
    } else if (n < 128) {
        hist[n - 64] = 0;
    }
    __syncthreads();

    float a1 = jexp(f1) / jexp(f0);
    int k1 = (uu.x < a1) ? prop1 : pre;

    float a2 = jexp(esh[pt]) / jexp(esh[k1]);
    int z = (uu.y < a2) ? pt : k1;

    // only LDS atomics before the final barrier
    atomicAdd(&hist[z], 1);
    atomicAdd(&hist[pre], -1);
    __syncthreads();

    // ---- phase C: global writes, fire-and-forget ----
    z_out[r * NN + n] = (float)z;
    if (z != pre) {   // net-zero when equal
        size_t rowbase = ((size_t)t * V + w) * 16;   // K/4 u32 per row
        atomicAdd(&plus [rowbase + (z   >> 2)], 1u << ((z   & 3) * 8));
        atomicAdd(&minus[rowbase + (pre >> 2)], 1u << ((pre & 3) * 8));
    }
    if (n < K) {
        CDK_new[r * K + n] = cdk + (float)hist[n];   // block owns this row
    }
}

// ---------------- S finalize + CK_new += sum_d (CDKn - CDK) ----------------
// grid = 64 blocks (16 per t), 256 threads; CK_new pre-initialized with CK.
__global__ void reduce_kernel(const float* __restrict__ S_part,
                              const float* __restrict__ CDKn,
                              const float* __restrict__ CDK,
                              float* __restrict__ S,
                              float* __restrict__ CK_new)
{
    int b = blockIdx.x;
    int tid = threadIdx.x;

    if (b < 4 && tid < 64) {            // S finalize for t = b
        float s = 0.0f;
        #pragma unroll 5
        for (int i = 0; i < 125; ++i)
            s += S_part[(b * 125 + i) * 64 + tid];
        S[b * 64 + tid] = s;
    }

    int t  = b >> 4;
    int k  = tid & 63;
    int dl = tid >> 6;                  // 0..3
    int dbase = (b & 15) << 6;          // 16 chunks of 64 d's per t
    float s = 0.0f;
    #pragma unroll
    for (int i = 0; i < 16; ++i) {
        int d = dbase + dl + (i << 2);
        size_t idx = ((size_t)(t << 10) + d) * 64 + k;
        s += CDKn[idx] - CDK[idx];
    }
    __shared__ float sm[256];
    sm[tid] = s;
    __syncthreads();
    if (tid < 64) {
        float tot = sm[k] + sm[k + 64] + sm[k + 128] + sm[k + 192];
        if (tot != 0.0f) atomicAdd(&CK_new[(t << 6) + k], tot);
    }
}

// ---------------- phi SGLD update + CWK_new materialization ----------------
// grid = VK/1024 = 2000 blocks; each thread owns 4 consecutive (v,k) slots.
__global__ void phi_update_kernel(const float* __restrict__ phi,
                                  const float* __restrict__ CWK,
                                  const unsigned int* __restrict__ plus,
                                  const unsigned int* __restrict__ minus,
                                  const float* __restrict__ CKn,
                                  const float* __restrict__ S,
                                  const float* __restrict__ noise_phi,
                                  float* __restrict__ phi_new,
                                  float* __restrict__ CWK_new)
{
    int i4 = blockIdx.x * 256 + threadIdx.x;    // float4 index, < VK/4 = 512000
    int kg = i4 & 15;                           // k-group: k = 4*kg .. 4*kg+3
    const float eps = 0.01f;
    const float half_eps = 0.005f;
    const float sig = 1.0f / 1.01f;             // phi_sigma / PHI_VAR

    const float4* phi4  = (const float4*)phi;
    const float4* cwk4  = (const float4*)CWK;
    const float4* ck4   = (const float4*)CKn;
    const float4* s4    = (const float4*)S;
    float4*       out4  = (float4*)phi_new;
    float4*       cwkn4 = (float4*)CWK_new;

    float4 p0 = phi4[i4];
    float4 p1 = phi4[i4 +     512000];
    float4 p2 = phi4[i4 + 2 * 512000];
    float4 p3 = phi4[i4 + 3 * 512000];

    float4 c0 = cwk4[i4];
    float4 c1 = cwk4[i4 +     512000];
    float4 c2 = cwk4[i4 + 2 * 512000];
    float4 c3 = cwk4[i4 + 3 * 512000];

    unsigned int pl0 = plus [i4],               mi0 = minus[i4];
    unsigned int pl1 = plus [i4 +     512000],  mi1 = minus[i4 +     512000];
    unsigned int pl2 = plus [i4 + 2 * 512000],  mi2 = minus[i4 + 2 * 512000];
    unsigned int pl3 = plus [i4 + 3 * 512000],  mi3 = minus[i4 + 3 * 512000];

    float4 ckn0 = ck4[kg],      ckn1 = ck4[16 + kg];
    float4 ckn2 = ck4[32 + kg], ckn3 = ck4[48 + kg];
    float4 ss0 = s4[kg],        ss1 = s4[16 + kg];
    float4 ss2 = s4[32 + kg],   ss3 = s4[48 + kg];

    float np0 = noise_phi[0] * eps, np1 = noise_phi[1] * eps;
    float np2 = noise_phi[2] * eps, np3 = noise_phi[3] * eps;

    float4 o0, o1, o2, o3, w0, w1, w2, w3;
    #pragma unroll
    for (int j = 0; j < 4; ++j) {
        int sh = j * 8;
        float q0 = (&p0.x)[j], q1 = (&p1.x)[j], q2 = (&p2.x)[j], q3 = (&p3.x)[j];
        float d0 = (float)((pl0 >> sh) & 255u) - (float)((mi0 >> sh) & 255u);
        float d1 = (float)((pl1 >> sh) & 255u) - (float)((mi1 >> sh) & 255u);
        float d2 = (float)((pl2 >> sh) & 255u) - (float)((mi2 >> sh) & 255u);
        float d3 = (float)((pl3 >> sh) & 255u) - (float)((mi3 >> sh) & 255u);
        float cw0 = (&c0.x)[j] + d0;
        float cw1 = (&c1.x)[j] + d1;
        float cw2 = (&c2.x)[j] + d2;
        float cw3 = (&c3.x)[j] + d3;
        (&w0.x)[j] = cw0; (&w1.x)[j] = cw1; (&w2.x)[j] = cw2; (&w3.x)[j] = cw3;

        float g0 = cw0 - (&ckn0.x)[j] * (expf(q0) / (&ss0.x)[j]);
        float g1 = cw1 - (&ckn1.x)[j] * (expf(q1) / (&ss1.x)[j]);
        float g2 = cw2 - (&ckn2.x)[j] * (expf(q2) / (&ss2.x)[j]);
        float g3 = cw3 - (&ckn3.x)[j] * (expf(q3) / (&ss3.x)[j]);

        float r0 = q0 + half_eps * (g0 + 2.0f * q1 * sig - 2.0f * q0) + np0;
        float r1 = q1 + half_eps * (g1 + q2 + r0 - 2.0f * q1)         + np1;
        float r2 = q2 + half_eps * (g2 + q3 + r1 - 2.0f * q2)         + np2;
        float r3 = q3 + half_eps * (g3 + r2 - q3)                      + np3;

        (&o0.x)[j] = r0; (&o1.x)[j] = r1; (&o2.x)[j] = r2; (&o3.x)[j] = r3;
    }

    out4[i4]              = o0;
    out4[i4 +     512000] = o1;
    out4[i4 + 2 * 512000] = o2;
    out4[i4 + 3 * 512000] = o3;

    cwkn4[i4]              = w0;
    cwkn4[i4 +     512000] = w1;
    cwkn4[i4 + 2 * 512000] = w2;
    cwkn4[i4 + 3 * 512000] = w3;
}

extern "C" void kernel_launch(void* const* d_in, const int* in_sizes, int n_in,
                              void* d_out, int out_size, void* d_ws, size_t ws_size,
                              hipStream_t stream)
{
    const int*   W         = (const int*)  d_in[0];
    const int*   Z         = (const int*)  d_in[1];
    const int*   pwi       = (const int*)  d_in[2];
    const int*   ptop      = (const int*)  d_in[3];
    const float* u_mh      = (const float*)d_in[4];
    const float* noise_eta = (const float*)d_in[5];
    const float* noise_phi = (const float*)d_in[6];
    const float* alpha     = (const float*)d_in[7];
    const float* phi       = (const float*)d_in[8];
    const float* eta       = (const float*)d_in[9];
    const float* CDK       = (const float*)d_in[10];
    const float* CWK       = (const float*)d_in[11];
    const float* CK        = (const float*)d_in[12];

    float* out     = (float*)d_out;
    float* eta_new = out;                               // T*D*K   = 262144
    float* phi_new = out + 262144;                      // T*V*K   = 8192000
    float* CDK_new = out + 8454144;                     // T*D*K   = 262144
    float* CWK_new = out + 8716288;                     // T*V*K   = 8192000
    float* CK_new  = out + 16908288;                    // T*K     = 256
    float* z_out   = out + 16908544;                    // T*D*N   = 1048576

    float* ws      = (float*)d_ws;
    float* S       = ws;                                // 256 floats
    float* S_part  = ws + 256;                          // 500*64 floats
    unsigned int* plus  = (unsigned int*)(ws + 256 + 32000);   // 8,192,000 B
    unsigned int* minus = plus + 2048000;                      // 8,192,000 B

    phi_colsum_kernel<<<T * 125, 256, 0, stream>>>(phi, S_part, plus, CK, CK_new);
    mh_eta_kernel<<<TD, 256, 0, stream>>>(W, Z, pwi, ptop, u_mh, phi,
                                          eta, alpha, noise_eta, CDK,
                                          eta_new, CDK_new, plus, minus, z_out);
    reduce_kernel<<<64, 256, 0, stream>>>(S_part, CDK_new, CDK, S, CK_new);
    phi_update_kernel<<<VK / 1024, 256, 0, stream>>>(phi, CWK, plus, minus,
                                                     CK_new, S, noise_phi,
                                                     phi_new, CWK_new);
}

// Round 6
// 265.146 us; speedup vs baseline: 1.0617x; 1.0208x over previous
//
#include <hip/hip_runtime.h>

#define T 4
#define D 1024
#define NN 256
#define K 64
#define V 32000
// derived
#define VK (V*K)          // 2048000
#define TD (T*D)          // 4096

__device__ __forceinline__ float jexp(float x) {
    // jax_exp: clip(exp(clip(x,-700,700)), 1e-6)
    x = fminf(fmaxf(x, -700.0f), 700.0f);
    return fmaxf(expf(x), 1e-6f);
}

// ws layout (floats): S[256] | S_part[500*64] | plus u8[T*V*K] | minus u8[T*V*K]
// plus/minus SEPARATE 8MB regions (R3/R5 layout): a token's +1/-1 pair spreads
// across memory channels (R4's adjacent-line pairing serialized: -7us).
// delta zeroed by hipMemsetAsync BEFORE the fused kernel (can't zero in-kernel:
// would race with mh-role blocks' atomics).

// ---------------- fused: colsum role (500 blocks) + eta/MH role (4096 blocks) ----
// mh runs at 4% VALU / 19% HBM (atomic-service-bound); the colsum streaming
// work co-schedules under its stalls nearly for free.
__global__ void fused_kernel(const int* __restrict__ W, const int* __restrict__ Z,
                             const int* __restrict__ pwi, const int* __restrict__ ptop,
                             const float* __restrict__ u, const float* __restrict__ phi,
                             const float* __restrict__ eta,
                             const float* __restrict__ alpha,
                             const float* __restrict__ noise_eta,
                             const float* __restrict__ CDK,
                             const float* __restrict__ CK,
                             float* __restrict__ S_part,
                             float* __restrict__ CK_new,
                             float* __restrict__ eta_new,
                             float* __restrict__ CDK_new,
                             unsigned int* __restrict__ plus,
                             unsigned int* __restrict__ minus,
                             float* __restrict__ z_out)
{
    int blk = blockIdx.x;
    int n = threadIdx.x;

    __shared__ float sm[256];       // colsum role
    __shared__ float esh[K];        // mh role
    __shared__ int   hist[K];

    if (blk < 500) {
        // ================= colsum role =================
        if (blk == 0) CK_new[n] = CK[n];        // T*K = 256 = blockDim
        int t = blk / 125;
        int vbase = (blk % 125) * 256;
        int k = n & 63;
        int rr = n >> 6;            // 0..3
        const float* base = phi + (size_t)t * VK;
        float s = 0.0f;
        #pragma unroll 4
        for (int it = 0; it < 64; ++it) {
            int v = vbase + it * 4 + rr;
            s += expf(base[v * K + k]);         // coalesced
        }
        sm[n] = s;
        __syncthreads();
        if (n < 64) {
            S_part[blk * 64 + n] = sm[n] + sm[n + 64] +
                                   sm[n + 128] + sm[n + 192];
        }
        return;
    }

    // ================= eta + MH role =================
    int b = blk - 500;                   // 500 % 8 == 4: (b&7)->XCD still bijective
    int r = ((b & 7) << 9) | (b >> 3);   // XCD-locality: one t per XCD-class
    int t = r >> 10;                     // D = 1024
;
    // ---- early independent token loads (issue before the eta barrier) ----
    int w     = W[r * NN + n];
    int pre   = Z[r * NN + n];          // coalesced; makes the row L1-hot
    int pw    = pwi[r * NN + n];
    int prop1 = Z[r * NN + pw];         // random-in-row: L1 hit
    int pt    = ptop[r * NN + n];
    float2 uu = ((const float2*)u)[(size_t)r * NN + n];

    const float* prow = phi + ((size_t)t * V + w) * K;
    float f1 = prow[prop1];             // scattered gathers, in flight during eta
    float f0 = prow[pre];

    float cdk = 0.0f;
    if (n < 64) {
        // ---- eta SGLD update for this row, wave 0 only ----
        float x = eta[r * K + n];
        float m = x;
        #pragma unroll
        for (int off = 32; off >= 1; off >>= 1)
            m = fmaxf(m, __shfl_xor(m, off, 64));
        float e = expf(x - m);
        float s = e;
        #pragma unroll
        for (int off = 32; off >= 1; off >>= 1)
            s += __shfl_xor(s, off, 64);
        float smx = e / s;
        cdk = CDK[r * K + n];
        float grad  = cdk - (float)NN * smx;
        float prior = alpha[t * K + n] - x;          // ETA_VAR = 1
        float en = x + 0.005f * (grad + prior) + noise_eta[r] * 0.01f;
        esh[n] = en;
        eta_new[r * K + n] = en;
    } else if (n < 128) {
        hist[n - 64] = 0;
    }
    __syncthreads();

    float a1 = jexp(f1) / jexp(f0);
    int k1 = (uu.x < a1) ? prop1 : pre;

    float a2 = jexp(esh[pt]) / jexp(esh[k1]);
    int z = (uu.y < a2) ? pt : k1;

    // only LDS atomics before the final barrier
    atomicAdd(&hist[z], 1);
    atomicAdd(&hist[pre], -1);
    __syncthreads();

    // ---- phase C: global writes, fire-and-forget ----
    z_out[r * NN + n] = (float)z;
    if (z != pre) {   // net-zero when equal
        size_t rowbase = ((size_t)t * V + w) * 16;   // K/4 u32 per row
        atomicAdd(&plus [rowbase + (z   >> 2)], 1u << ((z   & 3) * 8));
        atomicAdd(&minus[rowbase + (pre >> 2)], 1u << ((pre & 3) * 8));
    }
    if (n < K) {
        CDK_new[r * K + n] = cdk + (float)hist[n];   // block owns this row
    }
}

// ---------------- S finalize + CK_new += sum_d (CDKn - CDK) ----------------
// grid = 64 blocks (16 per t), 256 threads; CK_new pre-initialized with CK.
__global__ void reduce_kernel(const float* __restrict__ S_part,
                              const float* __restrict__ CDKn,
                              const float* __restrict__ CDK,
                              float* __restrict__ S,
                              float* __restrict__ CK_new)
{
    int b = blockIdx.x;
    int tid = threadIdx.x;

    if (b < 4 && tid < 64) {            // S finalize for t = b
        float s = 0.0f;
        #pragma unroll 5
        for (int i = 0; i < 125; ++i)
            s += S_part[(b * 125 + i) * 64 + tid];
        S[b * 64 + tid] = s;
    }

    int t  = b >> 4;
    int k  = tid & 63;
    int dl = tid >> 6;                  // 0..3
    int dbase = (b & 15) << 6;          // 16 chunks of 64 d's per t
    float s = 0.0f;
    #pragma unroll
    for (int i = 0; i < 16; ++i) {
        int d = dbase + dl + (i << 2);
        size_t idx = ((size_t)(t << 10) + d) * 64 + k;
        s += CDKn[idx] - CDK[idx];
    }
    __shared__ float sm[256];
    sm[tid] = s;
    __syncthreads();
    if (tid < 64) {
        float tot = sm[k] + sm[k + 64] + sm[k + 128] + sm[k + 192];
        if (tot != 0.0f) atomicAdd(&CK_new[(t << 6) + k], tot);
    }
}

// ---------------- phi SGLD update + CWK_new materialization ----------------
// grid = VK/1024 = 2000 blocks; each thread owns 4 consecutive (v,k) slots.
__global__ void phi_update_kernel(const float* __restrict__ phi,
                                  const float* __restrict__ CWK,
                                  const unsigned int* __restrict__ plus,
                                  const unsigned int* __restrict__ minus,
                                  const float* __restrict__ CKn,
                                  const float* __restrict__ S,
                                  const float* __restrict__ noise_phi,
                                  float* __restrict__ phi_new,
                                  float* __restrict__ CWK_new)
{
    int i4 = blockIdx.x * 256 + threadIdx.x;    // float4 index, < VK/4 = 512000
    int kg = i4 & 15;                           // k-group: k = 4*kg .. 4*kg+3
    const float eps = 0.01f;
    const float half_eps = 0.005f;
    const float sig = 1.0f / 1.01f;             // phi_sigma / PHI_VAR

    const float4* phi4  = (const float4*)phi;
    const float4* cwk4  = (const float4*)CWK;
    const float4* ck4   = (const float4*)CKn;
    const float4* s4    = (const float4*)S;
    float4*       out4  = (float4*)phi_new;
    float4*       cwkn4 = (float4*)CWK_new;

    float4 p0 = phi4[i4];
    float4 p1 = phi4[i4 +     512000];
    float4 p2 = phi4[i4 + 2 * 512000];
    float4 p3 = phi4[i4 + 3 * 512000];

    float4 c0 = cwk4[i4];
    float4 c1 = cwk4[i4 +     512000];
    float4 c2 = cwk4[i4 + 2 * 512000];
    float4 c3 = cwk4[i4 + 3 * 512000];

    unsigned int pl0 = plus [i4],               mi0 = minus[i4];
    unsigned int pl1 = plus [i4 +     512000],  mi1 = minus[i4 +     512000];
    unsigned int pl2 = plus [i4 + 2 * 512000],  mi2 = minus[i4 + 2 * 512000];
    unsigned int pl3 = plus [i4 + 3 * 512000],  mi3 = minus[i4 + 3 * 512000];

    float4 ckn0 = ck4[kg],      ckn1 = ck4[16 + kg];
    float4 ckn2 = ck4[32 + kg], ckn3 = ck4[48 + kg];
    float4 ss0 = s4[kg],        ss1 = s4[16 + kg];
    float4 ss2 = s4[32 + kg],   ss3 = s4[48 + kg];

    float np0 = noise_phi[0] * eps, np1 = noise_phi[1] * eps;
    float np2 = noise_phi[2] * eps, np3 = noise_phi[3] * eps;

    float4 o0, o1, o2, o3, w0, w1, w2, w3;
    #pragma unroll
    for (int j = 0; j < 4; ++j) {
        int sh = j * 8;
        float q0 = (&p0.x)[j], q1 = (&p1.x)[j], q2 = (&p2.x)[j], q3 = (&p3.x)[j];
        float d0 = (float)((pl0 >> sh) & 255u) - (float)((mi0 >> sh) & 255u);
        float d1 = (float)((pl1 >> sh) & 255u) - (float)((mi1 >> sh) & 255u);
        float d2 = (float)((pl2 >> sh) & 255u) - (float)((mi2 >> sh) & 255u);
        float d3 = (float)((pl3 >> sh) & 255u) - (float)((mi3 >> sh) & 255u);
        float cw0 = (&c0.x)[j] + d0;
        float cw1 = (&c1.x)[j] + d1;
        float cw2 = (&c2.x)[j] + d2;
        float cw3 = (&c3.x)[j] + d3;
        (&w0.x)[j] = cw0; (&w1.x)[j] = cw1; (&w2.x)[j] = cw2; (&w3.x)[j] = cw3;

        float g0 = cw0 - (&ckn0.x)[j] * (expf(q0) / (&ss0.x)[j]);
        float g1 = cw1 - (&ckn1.x)[j] * (expf(q1) / (&ss1.x)[j]);
        float g2 = cw2 - (&ckn2.x)[j] * (expf(q2) / (&ss2.x)[j]);
        float g3 = cw3 - (&ckn3.x)[j] * (expf(q3) / (&ss3.x)[j]);

        float r0 = q0 + half_eps * (g0 + 2.0f * q1 * sig - 2.0f * q0) + np0;
        float r1 = q1 + half_eps * (g1 + q2 + r0 - 2.0f * q1)         + np1;
        float r2 = q2 + half_eps * (g2 + q3 + r1 - 2.0f * q2)         + np2;
        float r3 = q3 + half_eps * (g3 + r2 - q3)                      + np3;

        (&o0.x)[j] = r0; (&o1.x)[j] = r1; (&o2.x)[j] = r2; (&o3.x)[j] = r3;
    }

    out4[i4]              = o0;
    out4[i4 +     512000] = o1;
    out4[i4 + 2 * 512000] = o2;
    out4[i4 + 3 * 512000] = o3;

    cwkn4[i4]              = w0;
    cwkn4[i4 +     512000] = w1;
    cwkn4[i4 + 2 * 512000] = w2;
    cwkn4[i4 + 3 * 512000] = w3;
}

extern "C" void kernel_launch(void* const* d_in, const int* in_sizes, int n_in,
                              void* d_out, int out_size, void* d_ws, size_t ws_size,
                              hipStream_t stream)
{
    const int*   W         = (const int*)  d_in[0];
    const int*   Z         = (const int*)  d_in[1];
    const int*   pwi       = (const int*)  d_in[2];
    const int*   ptop      = (const int*)  d_in[3];
    const float* u_mh      = (const float*)d_in[4];
    const float* noise_eta = (const float*)d_in[5];
    const float* noise_phi = (const float*)d_in[6];
    const float* alpha     = (const float*)d_in[7];
    const float* phi       = (const float*)d_in[8];
    const float* eta       = (const float*)d_in[9];
    const float* CDK       = (const float*)d_in[10];
    const float* CWK       = (const float*)d_in[11];
    const float* CK        = (const float*)d_in[12];

    float* out     = (float*)d_out;
    float* eta_new = out;                               // T*D*K   = 262144
    float* phi_new = out + 262144;                      // T*V*K   = 8192000
    float* CDK_new = out + 8454144;                     // T*D*K   = 262144
    float* CWK_new = out + 8716288;                     // T*V*K   = 8192000
    float* CK_new  = out + 16908288;                    // T*K     = 256
    float* z_out   = out + 16908544;                    // T*D*N   = 1048576

    float* ws      = (float*)d_ws;
    float* S       = ws;                                // 256 floats
    float* S_part  = ws + 256;                          // 500*64 floats
    unsigned int* plus  = (unsigned int*)(ws + 256 + 32000);   // 8,192,000 B
    unsigned int* minus = plus + 2048000;                      // 8,192,000 B

    hipMemsetAsync(plus, 0, 2 * (size_t)VK * sizeof(unsigned int) / 1, stream) ;
    // (plus+minus are contiguous: 16,384,000 B zeroed in one DMA)

    fused_kernel<<<500 + TD, 256, 0, stream>>>(W, Z, pwi, ptop, u_mh, phi,
                                               eta, alpha, noise_eta, CDK, CK,
                                               S_part, CK_new,
                                               eta_new, CDK_new, plus, minus, z_out);
    reduce_kernel<<<64, 256, 0, stream>>>(S_part, CDK_new, CDK, S, CK_new);
    phi_update_kernel<<<VK / 1024, 256, 0, stream>>>(phi, CWK, plus, minus,
                                                     CK_new, S, noise_phi,
                                                     phi_new, CWK_new);
}